// Round 6
// baseline (128.676 us; speedup 1.0000x reference)
//
#include <hip/hip_runtime.h>
#include <hip/hip_bf16.h>
#include <math.h>

// ---------------------------------------------------------------------------
// GatedTinyMambaLayer: B=8, T=2048, DM=1024, DS=256
// s_prev = broadcast(prev_state) -> per-batch [8,256] precomputes (state_k).
// Pipeline: cvt_x -> prep_w -> state -> gemm1 (m97 128x128) -> fuse2
// (S-from-Y + gemm2 + h, full-K LDS, barrier-free loop) -> gemm3.
// ---------------------------------------------------------------------------

typedef __attribute__((ext_vector_type(4)))  float f32x4;
typedef __attribute__((ext_vector_type(8)))  short bf16x8;

#define DEV static __device__ __forceinline__

DEV float bf2f(short u) {
  union { float f; unsigned i; } v; v.i = ((unsigned)(unsigned short)u) << 16; return v.f;
}
DEV short f2bf(float f) {  // round-to-nearest-even
  union { float f; unsigned i; } v; v.f = f;
  unsigned x = v.i;
  return (short)((x + 0x7fffu + ((x >> 16) & 1u)) >> 16);
}
DEV unsigned pk_bf16(float lo, float hi) {  // -> v_cvt_pk_bf16_f32
  __hip_bfloat162 h = __float22bfloat162_rn(make_float2(lo, hi));
  return *(unsigned*)&h;
}
DEV float sigmoidf_(float x) { return 1.f / (1.f + expf(-x)); }

DEV void gl16(const void* g, void* l) {
  __builtin_amdgcn_global_load_lds(
      (const __attribute__((address_space(1))) void*)(g),
      (__attribute__((address_space(3))) void*)(l), 16, 0, 0);
}

// stage one 128x32 bf16 subtile pair into linear LDS [128][32] via gload_lds
DEV void stage_tile(const short* gA, const short* gB, short* As, short* Bs,
                    int lda, int ldb, int w, int lane) {
  const int rsub = lane >> 2, kc = (lane & 3) * 8;
#pragma unroll
  for (int j = 0; j < 2; ++j) {
    const int seg = w * 2 + j;           // 0..7, 16 rows each
    const int r = seg * 16 + rsub;
    gl16(gA + (size_t)r * lda + kc, As + seg * 512);
    gl16(gB + (size_t)r * ldb + kc, Bs + seg * 512);
  }
}

DEV void kstep(const short* Asb, const short* Bsb, int wr, int wc, int arow, int ag,
               f32x4 (&acc)[4][4]) {
  bf16x8 af[4], bfv[4];
#pragma unroll
  for (int mi = 0; mi < 4; ++mi)
    af[mi] = *(const bf16x8*)(Asb + (wr * 64 + mi * 16 + arow) * 32 + ag * 8);
#pragma unroll
  for (int ni = 0; ni < 4; ++ni)
    bfv[ni] = *(const bf16x8*)(Bsb + (wc * 64 + ni * 16 + arow) * 32 + ag * 8);
#pragma unroll
  for (int mi = 0; mi < 4; ++mi)
#pragma unroll
    for (int ni = 0; ni < 4; ++ni)
      acc[mi][ni] = __builtin_amdgcn_mfma_f32_16x16x32_bf16(af[mi], bfv[ni], acc[mi][ni], 0, 0, 0);
}

// ---- workspace layout (bytes) ---------------------------------------------
static const size_t OFF_Y    = 0;                   // bf16 [16384][768] = 24 MiB
static const size_t OFF_XBF  = 25165824;            // bf16 [16384][1024] = 32 MiB; H aliases (xbf dead after gemm1)
static const size_t OFF_WCAT = OFF_XBF + 33554432;  // bf16 [768][1024]
static const size_t OFF_WPP  = OFF_WCAT + 1572864;  // bf16 [256][256]  (W_pp[:, :256])
static const size_t OFF_WOUT = OFF_WPP + 131072;    // bf16 [1024][256]
static const size_t OFF_VEC  = OFF_WOUT + 524288;   // f32 [5][2048]: sdc,sws,spp,pstr,gst

// ---------------------------------------------------------------------------
// x f32 -> bf16, 8 elems/thread (2x float4 load, one 16B store)
__global__ __launch_bounds__(256, 1) void cvt_x_k(const float* __restrict__ x,
                                                  short* __restrict__ xbf) {
  const size_t i = ((size_t)blockIdx.x * 256 + threadIdx.x) * 8;
  const float4 a = *(const float4*)(x + i);
  const float4 b = *(const float4*)(x + i + 4);
  uint4 o;
  o.x = pk_bf16(a.x, a.y); o.y = pk_bf16(a.z, a.w);
  o.z = pk_bf16(b.x, b.y); o.w = pk_bf16(b.z, b.w);
  *(uint4*)(xbf + i) = o;
}

// ---------------------------------------------------------------------------
__global__ __launch_bounds__(256, 1) void prep_w_k(const float* __restrict__ W_in,
                                                   const float* __restrict__ W_x,
                                                   const float* __restrict__ W_gx,
                                                   const float* __restrict__ W_dc,
                                                   const float* __restrict__ W_pp,
                                                   const float* __restrict__ W_out,
                                                   short* __restrict__ wcat,
                                                   short* __restrict__ wpp,
                                                   short* __restrict__ wout) {
  const int idx = (int)blockIdx.x * 256 + (int)threadIdx.x;
  const int N_WCAT = 768 * 1024, N_WPP = 256 * 256;
  if (idx < N_WCAT) {
    const int r = idx >> 10, k = idx & 1023;
    float v;
    if (r < 256)      v = W_in[r * 1024 + k] + W_x[r * 1024 + k];
    else if (r < 512) v = W_gx[(r - 256) * 1024 + k];
    else              v = W_dc[(r - 512) * 1280 + k];
    wcat[idx] = f2bf(v);
  } else if (idx < N_WCAT + N_WPP) {
    const int j = idx - N_WCAT, o = j >> 8, k = j & 255;
    wpp[j] = f2bf(W_pp[o * 512 + k]);          // W_pp[:, :256] (s_pred part)
  } else {
    const int j = idx - N_WCAT - N_WPP, o = j >> 8, k = j & 255;
    wout[j] = f2bf(W_out[o * 256 + k]);
  }
}

// ---------------------------------------------------------------------------
// per-batch state GEMVs, coalesced: lanes span K (float4 each), butterfly reduce.
__global__ __launch_bounds__(256, 1) void state_k(const float* __restrict__ prev,
                                                  const float* __restrict__ Ws,
                                                  const float* __restrict__ Wdc,
                                                  const float* __restrict__ bdc,
                                                  const float* __restrict__ Wpp,
                                                  const float* __restrict__ bpp,
                                                  const float* __restrict__ Wpg,
                                                  const float* __restrict__ bpg,
                                                  const float* __restrict__ Wgs,
                                                  const float* __restrict__ bgs,
                                                  float* __restrict__ vecs) {
  const int bid = (int)blockIdx.x;
  const int b = bid / 20, rem = bid % 20, m = rem >> 2, oq = rem & 3;
  const int tid = (int)threadIdx.x, lane = tid & 63, w = tid >> 6;
  const float4 sv = *(const float4*)(prev + b * 256 + lane * 4);
  const float* Wb; const float* bias; int stride, off;
  if (m == 0)      { Wb = Wdc; stride = 1280; off = 1024; bias = bdc; }
  else if (m == 1) { Wb = Ws;  stride = 256;  off = 0;    bias = nullptr; }
  else if (m == 2) { Wb = Wpp; stride = 512;  off = 256;  bias = bpp; }
  else if (m == 3) { Wb = Wpg; stride = 256;  off = 0;    bias = bpg; }
  else             { Wb = Wgs; stride = 256;  off = 0;    bias = bgs; }
  const int o0 = oq * 64 + w * 16;
#pragma unroll 4
  for (int i = 0; i < 16; ++i) {
    const int o = o0 + i;
    const float4 wv = *(const float4*)(Wb + (size_t)o * stride + off + lane * 4);
    float p = wv.x * sv.x + wv.y * sv.y + wv.z * sv.z + wv.w * sv.w;
#pragma unroll
    for (int d = 32; d >= 1; d >>= 1) p += __shfl_xor(p, d, 64);
    if (lane == 0) {
      float r = (m == 1) ? 0.5f * p : p + bias[o];
      if (m >= 3) r = sigmoidf_(r);
      vecs[m * 2048 + b * 256 + o] = r;
    }
  }
}

// ---------------------------------------------------------------------------
// GEMM1: Y[16384][768] bf16 = xbf @ wcat^T.  K=1024 -> 32 k-steps. (m97 form)
__global__ __launch_bounds__(256) void gemm1_k(const short* __restrict__ A,
                                               const short* __restrict__ Bm,
                                               short* __restrict__ Y) {
  __shared__ short As[2][4096];
  __shared__ short Bs[2][4096];
  const int tid = (int)threadIdx.x, lane = tid & 63, w = tid >> 6;
  const int wr = w >> 1, wc = w & 1;
  int bid = (int)blockIdx.x;
  bid = (bid & 7) * 96 + (bid >> 3);           // XCD swizzle (768 % 8 == 0)
  const int m0 = (bid / 6) * 128, n0 = (bid % 6) * 128;
  const short* gA = A + (size_t)m0 * 1024;
  const short* gB = Bm + (size_t)n0 * 1024;

  f32x4 acc[4][4];
#pragma unroll
  for (int mi = 0; mi < 4; ++mi)
#pragma unroll
    for (int ni = 0; ni < 4; ++ni)
#pragma unroll
      for (int r = 0; r < 4; ++r) acc[mi][ni][r] = 0.f;

  stage_tile(gA, gB, As[0], Bs[0], 1024, 1024, w, lane);
  __syncthreads();
  const int arow = lane & 15, ag = lane >> 4;
#pragma unroll 1
  for (int t = 0; t < 32; ++t) {
    if (t < 31)
      stage_tile(gA + (t + 1) * 32, gB + (t + 1) * 32,
                 As[(t + 1) & 1], Bs[(t + 1) & 1], 1024, 1024, w, lane);
    kstep(As[t & 1], Bs[t & 1], wr, wc, arow, ag, acc);
    __syncthreads();
  }
#pragma unroll
  for (int mi = 0; mi < 4; ++mi)
#pragma unroll
    for (int ni = 0; ni < 4; ++ni) {
      const int col = n0 + wc * 64 + ni * 16 + (lane & 15);
#pragma unroll
      for (int r = 0; r < 4; ++r) {
        const int row = m0 + wr * 64 + mi * 16 + (lane >> 4) * 4 + r;
        Y[(size_t)row * 768 + col] = f2bf(acc[mi][ni][r]);
      }
    }
}

// ---------------------------------------------------------------------------
// fuse2: per 128x128 tile of P = S @ wpp^T:
//   - compute S[128][256] from Y (on the fly) into XOR-swizzled LDS (full K)
//   - stage wpp n-slice [128][256] via global_load_lds with inverse-swizzled
//     global source (rule: linear dest + pre-swizzled src + swizzled read)
//   - barrier-free 8-step MFMA loop (full K resident)
//   - epilogue: h = (S + pstr*tanh(P+spp)) * sig(Ygx+bgx) * gst -> H bf16
// Replaces elem1 + gemm2h. grid = 128 m-tiles x 2 n-tiles = 256 blocks.
__global__ __launch_bounds__(256, 1) void fuse2_k(const short* __restrict__ Y,
                                                  const float* __restrict__ prev,
                                                  const float* __restrict__ bgx,
                                                  const float* __restrict__ vecs,
                                                  const short* __restrict__ Wpp,
                                                  short* __restrict__ H,
                                                  float* __restrict__ out) {
  __shared__ short Sl[32768];   // [128][32 granules of 8 bf16], granule^=(row&7)
  __shared__ short Bl[32768];   // same layout for wpp slice
  const int tid = (int)threadIdx.x, lane = tid & 63, w = tid >> 6;
  const int wr = w >> 1, wc = w & 1;
  int bid = (int)blockIdx.x;
  bid = (bid & 7) * 32 + (bid >> 3);           // 256 % 8 == 0, bijective
  const int m0 = (bid >> 1) * 128, n0 = (bid & 1) * 128;
  const int b = m0 >> 11;

  // ---- stage B (wpp rows n0..n0+127, full K=256): linear LDS dest,
  //      global source granule pre-swizzled gs = gc ^ (r&7)
  {
    const int G0 = w * 64 + lane;              // granule idx within round
#pragma unroll
    for (int i = 0; i < 16; ++i) {
      const int G = i * 256 + G0;
      const int r = G >> 5, gc = G & 31, gs = gc ^ (r & 7);
      gl16(Wpp + (size_t)(n0 + r) * 256 + gs * 8, Bl + (i * 256 + w * 64) * 8);
    }
  }
  // ---- compute S rows -> swizzled LDS (reg-staged ds_write)
  {
    const int r = tid >> 1, k0 = (tid & 1) * 128;
    const int row = m0 + r;
    const float* pv = prev + b * 256;
    const float* sd = vecs + 0 * 2048 + b * 256;
    const float* sw = vecs + 1 * 2048 + b * 256;
#pragma unroll
    for (int j = 0; j < 16; ++j) {
      const int k = k0 + j * 8;
      const bf16x8 yix = *(const bf16x8*)(Y + (size_t)row * 768 + k);
      const bf16x8 ydc = *(const bf16x8*)(Y + (size_t)row * 768 + 512 + k);
      const float4 p0 = *(const float4*)(pv + k), p1 = *(const float4*)(pv + k + 4);
      const float4 d0 = *(const float4*)(sd + k), d1 = *(const float4*)(sd + k + 4);
      const float4 s0 = *(const float4*)(sw + k), s1 = *(const float4*)(sw + k + 4);
      float sp[8];
      const float pd[8] = {p0.x, p0.y, p0.z, p0.w, p1.x, p1.y, p1.z, p1.w};
      const float dd[8] = {d0.x, d0.y, d0.z, d0.w, d1.x, d1.y, d1.z, d1.w};
      const float sd8[8] = {s0.x, s0.y, s0.z, s0.w, s1.x, s1.y, s1.z, s1.w};
#pragma unroll
      for (int e = 0; e < 8; ++e) {
        const float dec = expf(-0.05f * sigmoidf_(bf2f(ydc[e]) + dd[e]));
        sp[e] = pd[e] * dec + bf2f(yix[e]) + sd8[e];
      }
      uint4 pk;
      pk.x = pk_bf16(sp[0], sp[1]); pk.y = pk_bf16(sp[2], sp[3]);
      pk.z = pk_bf16(sp[4], sp[5]); pk.w = pk_bf16(sp[6], sp[7]);
      const int gc = k >> 3;
      *(uint4*)(Sl + (r * 32 + (gc ^ (r & 7))) * 8) = pk;
    }
  }
  __syncthreads();  // drains gl16 vmcnt + publishes ds_writes

  // ---- barrier-free MFMA loop over K=256 (8 steps), swizzled reads
  const int arow = lane & 15, ag = lane >> 4;
  f32x4 acc[4][4];
#pragma unroll
  for (int mi = 0; mi < 4; ++mi)
#pragma unroll
    for (int ni = 0; ni < 4; ++ni)
#pragma unroll
      for (int r = 0; r < 4; ++r) acc[mi][ni][r] = 0.f;
#pragma unroll
  for (int t = 0; t < 8; ++t) {
    bf16x8 af[4], bfv[4];
#pragma unroll
    for (int mi = 0; mi < 4; ++mi) {
      const int rr = wr * 64 + mi * 16 + arow;
      af[mi] = *(const bf16x8*)(Sl + (rr * 32 + ((t * 4 + ag) ^ (rr & 7))) * 8);
    }
#pragma unroll
    for (int ni = 0; ni < 4; ++ni) {
      const int rr = wc * 64 + ni * 16 + arow;
      bfv[ni] = *(const bf16x8*)(Bl + (rr * 32 + ((t * 4 + ag) ^ (rr & 7))) * 8);
    }
#pragma unroll
    for (int mi = 0; mi < 4; ++mi)
#pragma unroll
      for (int ni = 0; ni < 4; ++ni)
        acc[mi][ni] = __builtin_amdgcn_mfma_f32_16x16x32_bf16(af[mi], bfv[ni], acc[mi][ni], 0, 0, 0);
  }

  // ---- epilogue
#pragma unroll
  for (int mi = 0; mi < 4; ++mi)
#pragma unroll
    for (int ni = 0; ni < 4; ++ni) {
      const int cg = n0 + wc * 64 + ni * 16 + (lane & 15);   // DS col 0..255
      const float spp  = vecs[2 * 2048 + b * 256 + cg];
      const float pstr = vecs[3 * 2048 + b * 256 + cg];
      const float gst  = vecs[4 * 2048 + b * 256 + cg];
      const float bg   = bgx[cg];
#pragma unroll
      for (int r = 0; r < 4; ++r) {
        const int rloc = wr * 64 + mi * 16 + (lane >> 4) * 4 + r;
        const int row = m0 + rloc;
        const float pvv = tanhf(acc[mi][ni][r] + spp);
        const float sp = bf2f(Sl[(rloc * 32 + ((cg >> 3) ^ (rloc & 7))) * 8 + (cg & 7)]);
        const float gi = sigmoidf_(bf2f(Y[(size_t)row * 768 + 256 + cg]) + bg);
        const float h = (sp + pstr * pvv) * gi * gst;
        H[(size_t)row * 256 + cg] = f2bf(h);
        if ((row & 2047) == 2047) out[16777216 + b * 256 + cg] = h;
      }
    }
}

// ---------------------------------------------------------------------------
// GEMM3: out[16384][1024] f32 = H @ wout^T. K=256 -> 8 k-steps. (m97 form)
__global__ __launch_bounds__(256) void gemm3_k(const short* __restrict__ H,
                                               const short* __restrict__ Wout,
                                               float* __restrict__ out) {
  __shared__ short As[2][4096];
  __shared__ short Bs[2][4096];
  const int tid = (int)threadIdx.x, lane = tid & 63, w = tid >> 6;
  const int wr = w >> 1, wc = w & 1;
  int bid = (int)blockIdx.x;
  bid = (bid & 7) * 128 + (bid >> 3);          // 1024 % 8 == 0
  const int m0 = (bid >> 3) * 128, n0 = (bid & 7) * 128;
  const short* gA = H + (size_t)m0 * 256;
  const short* gB = Wout + (size_t)n0 * 256;

  f32x4 acc[4][4];
#pragma unroll
  for (int mi = 0; mi < 4; ++mi)
#pragma unroll
    for (int ni = 0; ni < 4; ++ni)
#pragma unroll
      for (int r = 0; r < 4; ++r) acc[mi][ni][r] = 0.f;

  stage_tile(gA, gB, As[0], Bs[0], 256, 256, w, lane);
  __syncthreads();
  const int arow = lane & 15, ag = lane >> 4;
#pragma unroll 1
  for (int t = 0; t < 8; ++t) {
    if (t < 7)
      stage_tile(gA + (t + 1) * 32, gB + (t + 1) * 32,
                 As[(t + 1) & 1], Bs[(t + 1) & 1], 256, 256, w, lane);
    kstep(As[t & 1], Bs[t & 1], wr, wc, arow, ag, acc);
    __syncthreads();
  }
#pragma unroll
  for (int mi = 0; mi < 4; ++mi)
#pragma unroll
    for (int ni = 0; ni < 4; ++ni) {
      const int col = n0 + wc * 64 + ni * 16 + (lane & 15);
#pragma unroll
      for (int r = 0; r < 4; ++r) {
        const int row = m0 + wr * 64 + mi * 16 + (lane >> 4) * 4 + r;
        out[(size_t)row * 1024 + col] = acc[mi][ni][r];
      }
    }
}

// ---------------------------------------------------------------------------
extern "C" void kernel_launch(void* const* d_in, const int* in_sizes, int n_in,
                              void* d_out, int out_size, void* d_ws, size_t ws_size,
                              hipStream_t stream) {
  (void)in_sizes; (void)n_in; (void)out_size; (void)ws_size;
  const float* x      = (const float*)d_in[0];
  const float* prev   = (const float*)d_in[1];
  const float* W_in   = (const float*)d_in[2];
  const float* W_x    = (const float*)d_in[3];
  const float* W_s    = (const float*)d_in[4];
  const float* W_out  = (const float*)d_in[5];
  const float* W_gx   = (const float*)d_in[6];
  const float* b_gx   = (const float*)d_in[7];
  const float* W_gs   = (const float*)d_in[8];
  const float* b_gs   = (const float*)d_in[9];
  const float* W_dc   = (const float*)d_in[10];
  const float* b_dc   = (const float*)d_in[11];
  const float* W_pp   = (const float*)d_in[12];
  const float* b_pp   = (const float*)d_in[13];
  const float* W_pg   = (const float*)d_in[14];
  const float* b_pg   = (const float*)d_in[15];

  char* ws = (char*)d_ws;
  short* Y    = (short*)(ws + OFF_Y);
  short* xbf  = (short*)(ws + OFF_XBF);
  short* H    = (short*)(ws + OFF_XBF);   // aliases xbf (dead after gemm1)
  short* wcat = (short*)(ws + OFF_WCAT);
  short* wpp  = (short*)(ws + OFF_WPP);
  short* wout = (short*)(ws + OFF_WOUT);
  float* vecs = (float*)(ws + OFF_VEC);
  float* out  = (float*)d_out;

  cvt_x_k<<<8192, 256, 0, stream>>>(x, xbf);
  prep_w_k<<<4352, 256, 0, stream>>>(W_in, W_x, W_gx, W_dc, W_pp, W_out, wcat, wpp, wout);
  state_k<<<160, 256, 0, stream>>>(prev, W_s, W_dc, b_dc, W_pp, b_pp, W_pg, b_pg, W_gs, b_gs, vecs);
  gemm1_k<<<768, 256, 0, stream>>>(xbf, wcat, Y);
  fuse2_k<<<256, 256, 0, stream>>>(Y, prev, b_gx, vecs, wpp, H, out);
  gemm3_k<<<1024, 256, 0, stream>>>(H, wout, out);
}

// Round 7
// 115.410 us; speedup vs baseline: 1.1149x; 1.1149x over previous
//
#include <hip/hip_runtime.h>
#include <hip/hip_bf16.h>
#include <math.h>

// ---------------------------------------------------------------------------
// GatedTinyMambaLayer: B=8, T=2048, DM=1024, DS=256
// s_prev = broadcast(prev_state) -> per-batch [8,256] precomputes (state_k).
// Pipeline: cvt_x -> prep_w -> state -> gemm1sg (128x192 tile, epilogue
// computes S,G directly; Y never materialized) -> gemm2h -> gemm3.
// wcat row order: group g (0..3): [W_in+W_x rows g*64.., W_gx g*64..,
// W_dc g*64..] so one block's n-tile holds the full (ix,gx,dc) triple.
// ---------------------------------------------------------------------------

typedef __attribute__((ext_vector_type(4)))  float f32x4;
typedef __attribute__((ext_vector_type(8)))  short bf16x8;

#define DEV static __device__ __forceinline__

DEV float bf2f(short u) {
  union { float f; unsigned i; } v; v.i = ((unsigned)(unsigned short)u) << 16; return v.f;
}
DEV short f2bf(float f) {  // round-to-nearest-even
  union { float f; unsigned i; } v; v.f = f;
  unsigned x = v.i;
  return (short)((x + 0x7fffu + ((x >> 16) & 1u)) >> 16);
}
DEV unsigned pk_bf16(float lo, float hi) {  // -> v_cvt_pk_bf16_f32
  __hip_bfloat162 h = __float22bfloat162_rn(make_float2(lo, hi));
  return *(unsigned*)&h;
}
DEV float sigmoidf_(float x) { return 1.f / (1.f + expf(-x)); }

DEV void gl16(const void* g, void* l) {
  __builtin_amdgcn_global_load_lds(
      (const __attribute__((address_space(1))) void*)(g),
      (__attribute__((address_space(3))) void*)(l), 16, 0, 0);
}

// stage one 128x32 bf16 subtile pair into linear LDS [128][32] via gload_lds
DEV void stage_tile(const short* gA, const short* gB, short* As, short* Bs,
                    int lda, int ldb, int w, int lane) {
  const int rsub = lane >> 2, kc = (lane & 3) * 8;
#pragma unroll
  for (int j = 0; j < 2; ++j) {
    const int seg = w * 2 + j;           // 0..7, 16 rows each
    const int r = seg * 16 + rsub;
    gl16(gA + (size_t)r * lda + kc, As + seg * 512);
    gl16(gB + (size_t)r * ldb + kc, Bs + seg * 512);
  }
}

DEV void kstep(const short* Asb, const short* Bsb, int wr, int wc, int arow, int ag,
               f32x4 (&acc)[4][4]) {
  bf16x8 af[4], bfv[4];
#pragma unroll
  for (int mi = 0; mi < 4; ++mi)
    af[mi] = *(const bf16x8*)(Asb + (wr * 64 + mi * 16 + arow) * 32 + ag * 8);
#pragma unroll
  for (int ni = 0; ni < 4; ++ni)
    bfv[ni] = *(const bf16x8*)(Bsb + (wc * 64 + ni * 16 + arow) * 32 + ag * 8);
#pragma unroll
  for (int mi = 0; mi < 4; ++mi)
#pragma unroll
    for (int ni = 0; ni < 4; ++ni)
      acc[mi][ni] = __builtin_amdgcn_mfma_f32_16x16x32_bf16(af[mi], bfv[ni], acc[mi][ni], 0, 0, 0);
}

// ---- workspace layout (bytes) ---------------------------------------------
static const size_t OFF_S    = 0;                   // bf16 [16384][256]
static const size_t OFF_G    = 8388608;             // bf16 [16384][256]
static const size_t OFF_XBF  = 25165824;            // bf16 [16384][1024]; H aliases (dead after gemm1)
static const size_t OFF_WCAT = OFF_XBF + 33554432;  // bf16 [768][1024] (reordered)
static const size_t OFF_WPP  = OFF_WCAT + 1572864;  // bf16 [256][256]  (W_pp[:, :256])
static const size_t OFF_WOUT = OFF_WPP + 131072;    // bf16 [1024][256]
static const size_t OFF_VEC  = OFF_WOUT + 524288;   // f32 [5][2048]: sdc,sws,spp,pstr,gst

// ---------------------------------------------------------------------------
// x f32 -> bf16, 8 elems/thread
__global__ __launch_bounds__(256, 1) void cvt_x_k(const float* __restrict__ x,
                                                  short* __restrict__ xbf) {
  const size_t i = ((size_t)blockIdx.x * 256 + threadIdx.x) * 8;
  const float4 a = *(const float4*)(x + i);
  const float4 b = *(const float4*)(x + i + 4);
  uint4 o;
  o.x = pk_bf16(a.x, a.y); o.y = pk_bf16(a.z, a.w);
  o.z = pk_bf16(b.x, b.y); o.w = pk_bf16(b.z, b.w);
  *(uint4*)(xbf + i) = o;
}

// ---------------------------------------------------------------------------
// wcat rows (reordered): r = g*192 + j. j<64: W_in+W_x[g*64+j]; j<128:
// W_gx[g*64+j-64]; else W_dc[g*64+j-128][:1024].
__global__ __launch_bounds__(256, 1) void prep_w_k(const float* __restrict__ W_in,
                                                   const float* __restrict__ W_x,
                                                   const float* __restrict__ W_gx,
                                                   const float* __restrict__ W_dc,
                                                   const float* __restrict__ W_pp,
                                                   const float* __restrict__ W_out,
                                                   short* __restrict__ wcat,
                                                   short* __restrict__ wpp,
                                                   short* __restrict__ wout) {
  const int idx = (int)blockIdx.x * 256 + (int)threadIdx.x;
  const int N_WCAT = 768 * 1024, N_WPP = 256 * 256;
  if (idx < N_WCAT) {
    const int r = idx >> 10, k = idx & 1023;
    const int g = r / 192, j = r % 192;
    float v;
    if (j < 64)       v = W_in[(g * 64 + j) * 1024 + k] + W_x[(g * 64 + j) * 1024 + k];
    else if (j < 128) v = W_gx[(g * 64 + j - 64) * 1024 + k];
    else              v = W_dc[(g * 64 + j - 128) * 1280 + k];
    wcat[idx] = f2bf(v);
  } else if (idx < N_WCAT + N_WPP) {
    const int j = idx - N_WCAT, o = j >> 8, k = j & 255;
    wpp[j] = f2bf(W_pp[o * 512 + k]);          // W_pp[:, :256] (s_pred part)
  } else {
    const int j = idx - N_WCAT - N_WPP, o = j >> 8, k = j & 255;
    wout[j] = f2bf(W_out[o * 256 + k]);
  }
}

// ---------------------------------------------------------------------------
// per-batch state GEMVs, coalesced: lanes span K (float4 each), butterfly reduce.
__global__ __launch_bounds__(256, 1) void state_k(const float* __restrict__ prev,
                                                  const float* __restrict__ Ws,
                                                  const float* __restrict__ Wdc,
                                                  const float* __restrict__ bdc,
                                                  const float* __restrict__ Wpp,
                                                  const float* __restrict__ bpp,
                                                  const float* __restrict__ Wpg,
                                                  const float* __restrict__ bpg,
                                                  const float* __restrict__ Wgs,
                                                  const float* __restrict__ bgs,
                                                  float* __restrict__ vecs) {
  const int bid = (int)blockIdx.x;
  const int b = bid / 20, rem = bid % 20, m = rem >> 2, oq = rem & 3;
  const int tid = (int)threadIdx.x, lane = tid & 63, w = tid >> 6;
  const float4 sv = *(const float4*)(prev + b * 256 + lane * 4);
  const float* Wb; const float* bias; int stride, off;
  if (m == 0)      { Wb = Wdc; stride = 1280; off = 1024; bias = bdc; }
  else if (m == 1) { Wb = Ws;  stride = 256;  off = 0;    bias = nullptr; }
  else if (m == 2) { Wb = Wpp; stride = 512;  off = 256;  bias = bpp; }
  else if (m == 3) { Wb = Wpg; stride = 256;  off = 0;    bias = bpg; }
  else             { Wb = Wgs; stride = 256;  off = 0;    bias = bgs; }
  const int o0 = oq * 64 + w * 16;
#pragma unroll 4
  for (int i = 0; i < 16; ++i) {
    const int o = o0 + i;
    const float4 wv = *(const float4*)(Wb + (size_t)o * stride + off + lane * 4);
    float p = wv.x * sv.x + wv.y * sv.y + wv.z * sv.z + wv.w * sv.w;
#pragma unroll
    for (int d = 32; d >= 1; d >>= 1) p += __shfl_xor(p, d, 64);
    if (lane == 0) {
      float r = (m == 1) ? 0.5f * p : p + bias[o];
      if (m >= 3) r = sigmoidf_(r);
      vecs[m * 2048 + b * 256 + o] = r;
    }
  }
}

// ---------------------------------------------------------------------------
// GEMM1+SG: 128x192 tile, 4 waves x (32 rows x 192 cols). K=1024, 32 k-steps.
// Epilogue: each thread holds the (ix,gx,dc) triple for its cols -> writes
// S = prev*exp(-.05*sig(dc+sdc)) + ix + sws ; G = sig(gx+bgx). No Y.
__global__ __launch_bounds__(256) void gemm1sg_k(const short* __restrict__ A,
                                                 const short* __restrict__ Bm,
                                                 const float* __restrict__ prev,
                                                 const float* __restrict__ bgx,
                                                 const float* __restrict__ vecs,
                                                 short* __restrict__ S,
                                                 short* __restrict__ G) {
  __shared__ short As[2][4096];    // [128][32]
  __shared__ short Bs[2][6144];    // [192][32]
  const int tid = (int)threadIdx.x, lane = tid & 63, w = tid >> 6;
  int bid = (int)blockIdx.x;
  bid = (bid & 7) * 64 + (bid >> 3);           // XCD swizzle (512 % 8 == 0)
  const int mt = bid >> 2, nt = bid & 3;
  const int m0 = mt * 128, b = m0 >> 11;
  const short* gA = A + (size_t)m0 * 1024;
  const short* gB = Bm + (size_t)(nt * 192) * 1024;
  const int rsub = lane >> 2, kc = (lane & 3) * 8;

  f32x4 acc[2][12];
#pragma unroll
  for (int mi = 0; mi < 2; ++mi)
#pragma unroll
    for (int ni = 0; ni < 12; ++ni)
#pragma unroll
      for (int r = 0; r < 4; ++r) acc[mi][ni][r] = 0.f;

  // staging: A 512 granules (2/thread), B 768 granules (3/thread)
#define STAGE1(buf, t)                                                        \
  {                                                                           \
    _Pragma("unroll")                                                         \
    for (int j = 0; j < 2; ++j) {                                             \
      const int seg = w * 2 + j;                                              \
      gl16(gA + (size_t)(seg * 16 + rsub) * 1024 + (t) * 32 + kc,             \
           As[buf] + seg * 512);                                              \
    }                                                                         \
    _Pragma("unroll")                                                         \
    for (int i = 0; i < 3; ++i) {                                             \
      const int Gr = i * 256 + w * 64 + lane;                                 \
      gl16(gB + (size_t)(Gr >> 2) * 1024 + (t) * 32 + ((Gr & 3) * 8),         \
           Bs[buf] + (i * 256 + w * 64) * 8);                                 \
    }                                                                         \
  }

  STAGE1(0, 0);
  __syncthreads();
  const int arow = lane & 15, ag = lane >> 4;
#pragma unroll 1
  for (int t = 0; t < 32; ++t) {
    if (t < 31) STAGE1((t + 1) & 1, t + 1);
    const short* Asb = As[t & 1];
    const short* Bsb = Bs[t & 1];
    bf16x8 af[2];
#pragma unroll
    for (int mi = 0; mi < 2; ++mi)
      af[mi] = *(const bf16x8*)(Asb + (w * 32 + mi * 16 + arow) * 32 + ag * 8);
#pragma unroll
    for (int ni = 0; ni < 12; ++ni) {
      const bf16x8 bf = *(const bf16x8*)(Bsb + (ni * 16 + arow) * 32 + ag * 8);
#pragma unroll
      for (int mi = 0; mi < 2; ++mi)
        acc[mi][ni] = __builtin_amdgcn_mfma_f32_16x16x32_bf16(af[mi], bf, acc[mi][ni], 0, 0, 0);
    }
    __syncthreads();
  }
#undef STAGE1

  // epilogue: cols c = cidx*16 + arow (cidx 0..3), cg = nt*64 + c
  const int quad = lane >> 4;
#pragma unroll
  for (int cidx = 0; cidx < 4; ++cidx) {
    const int cg = nt * 64 + cidx * 16 + arow;
    const float sdc = vecs[0 * 2048 + b * 256 + cg];
    const float sws = vecs[1 * 2048 + b * 256 + cg];
    const float pv  = prev[b * 256 + cg];
    const float bg  = bgx[cg];
#pragma unroll
    for (int mi = 0; mi < 2; ++mi)
#pragma unroll
      for (int r = 0; r < 4; ++r) {
        const int row = m0 + w * 32 + mi * 16 + quad * 4 + r;
        const float dec = expf(-0.05f * sigmoidf_(acc[mi][8 + cidx][r] + sdc));
        const float sp = pv * dec + acc[mi][cidx][r] + sws;
        const float g = sigmoidf_(acc[mi][4 + cidx][r] + bg);
        S[(size_t)row * 256 + cg] = f2bf(sp);
        G[(size_t)row * 256 + cg] = f2bf(g);
      }
  }
}

// ---------------------------------------------------------------------------
// GEMM2 + elementwise: P = S @ wpp^T; h = (S + pstr*tanh(P+spp)) * G * gst
__global__ __launch_bounds__(256) void gemm2h_k(const short* __restrict__ S,
                                                const short* __restrict__ G,
                                                const short* __restrict__ Wpp,
                                                const float* __restrict__ vecs,
                                                short* __restrict__ H,
                                                float* __restrict__ out) {
  __shared__ short As[2][4096];
  __shared__ short Bs[2][4096];
  const int tid = (int)threadIdx.x, lane = tid & 63, w = tid >> 6;
  const int wr = w >> 1, wc = w & 1;
  int bid = (int)blockIdx.x;
  bid = (bid & 7) * 32 + (bid >> 3);           // 256 % 8 == 0
  const int m0 = (bid >> 1) * 128, n0 = (bid & 1) * 128;
  const int b = m0 >> 11;
  const short* gA = S + (size_t)m0 * 256;
  const short* gB = Wpp + (size_t)n0 * 256;

  f32x4 acc[4][4];
#pragma unroll
  for (int mi = 0; mi < 4; ++mi)
#pragma unroll
    for (int ni = 0; ni < 4; ++ni)
#pragma unroll
      for (int r = 0; r < 4; ++r) acc[mi][ni][r] = 0.f;

  stage_tile(gA, gB, As[0], Bs[0], 256, 256, w, lane);
  __syncthreads();
  const int arow = lane & 15, ag = lane >> 4;
#pragma unroll 1
  for (int t = 0; t < 8; ++t) {
    if (t < 7)
      stage_tile(gA + (t + 1) * 32, gB + (t + 1) * 32,
                 As[(t + 1) & 1], Bs[(t + 1) & 1], 256, 256, w, lane);
    kstep(As[t & 1], Bs[t & 1], wr, wc, arow, ag, acc);
    __syncthreads();
  }
#pragma unroll
  for (int mi = 0; mi < 4; ++mi)
#pragma unroll
    for (int ni = 0; ni < 4; ++ni) {
      const int col = n0 + wc * 64 + ni * 16 + (lane & 15);
      const float spp  = vecs[2 * 2048 + b * 256 + col];
      const float pstr = vecs[3 * 2048 + b * 256 + col];
      const float gst  = vecs[4 * 2048 + b * 256 + col];
#pragma unroll
      for (int r = 0; r < 4; ++r) {
        const int row = m0 + wr * 64 + mi * 16 + (lane >> 4) * 4 + r;
        const float pv = tanhf(acc[mi][ni][r] + spp);
        const float sp = bf2f(S[(size_t)row * 256 + col]);
        const float h = (sp + pstr * pv) * bf2f(G[(size_t)row * 256 + col]) * gst;
        H[(size_t)row * 256 + col] = f2bf(h);
        if ((row & 2047) == 2047) out[16777216 + b * 256 + col] = h;
      }
    }
}

// ---------------------------------------------------------------------------
// GEMM3: out[16384][1024] f32 = H @ wout^T. K=256 -> 8 k-steps. (m97 form)
__global__ __launch_bounds__(256) void gemm3_k(const short* __restrict__ H,
                                               const short* __restrict__ Wout,
                                               float* __restrict__ out) {
  __shared__ short As[2][4096];
  __shared__ short Bs[2][4096];
  const int tid = (int)threadIdx.x, lane = tid & 63, w = tid >> 6;
  const int wr = w >> 1, wc = w & 1;
  int bid = (int)blockIdx.x;
  bid = (bid & 7) * 128 + (bid >> 3);          // 1024 % 8 == 0
  const int m0 = (bid >> 3) * 128, n0 = (bid & 7) * 128;
  const short* gA = H + (size_t)m0 * 256;
  const short* gB = Wout + (size_t)n0 * 256;

  f32x4 acc[4][4];
#pragma unroll
  for (int mi = 0; mi < 4; ++mi)
#pragma unroll
    for (int ni = 0; ni < 4; ++ni)
#pragma unroll
      for (int r = 0; r < 4; ++r) acc[mi][ni][r] = 0.f;

  stage_tile(gA, gB, As[0], Bs[0], 256, 256, w, lane);
  __syncthreads();
  const int arow = lane & 15, ag = lane >> 4;
#pragma unroll 1
  for (int t = 0; t < 8; ++t) {
    if (t < 7)
      stage_tile(gA + (t + 1) * 32, gB + (t + 1) * 32,
                 As[(t + 1) & 1], Bs[(t + 1) & 1], 256, 256, w, lane);
    kstep(As[t & 1], Bs[t & 1], wr, wc, arow, ag, acc);
    __syncthreads();
  }
#pragma unroll
  for (int mi = 0; mi < 4; ++mi)
#pragma unroll
    for (int ni = 0; ni < 4; ++ni) {
      const int col = n0 + wc * 64 + ni * 16 + (lane & 15);
#pragma unroll
      for (int r = 0; r < 4; ++r) {
        const int row = m0 + wr * 64 + mi * 16 + (lane >> 4) * 4 + r;
        out[(size_t)row * 1024 + col] = acc[mi][ni][r];
      }
    }
}

// ---------------------------------------------------------------------------
extern "C" void kernel_launch(void* const* d_in, const int* in_sizes, int n_in,
                              void* d_out, int out_size, void* d_ws, size_t ws_size,
                              hipStream_t stream) {
  (void)in_sizes; (void)n_in; (void)out_size; (void)ws_size;
  const float* x      = (const float*)d_in[0];
  const float* prev   = (const float*)d_in[1];
  const float* W_in   = (const float*)d_in[2];
  const float* W_x    = (const float*)d_in[3];
  const float* W_s    = (const float*)d_in[4];
  const float* W_out  = (const float*)d_in[5];
  const float* W_gx   = (const float*)d_in[6];
  const float* b_gx   = (const float*)d_in[7];
  const float* W_gs   = (const float*)d_in[8];
  const float* b_gs   = (const float*)d_in[9];
  const float* W_dc   = (const float*)d_in[10];
  const float* b_dc   = (const float*)d_in[11];
  const float* W_pp   = (const float*)d_in[12];
  const float* b_pp   = (const float*)d_in[13];
  const float* W_pg   = (const float*)d_in[14];
  const float* b_pg   = (const float*)d_in[15];

  char* ws = (char*)d_ws;
  short* S    = (short*)(ws + OFF_S);
  short* G    = (short*)(ws + OFF_G);
  short* xbf  = (short*)(ws + OFF_XBF);
  short* H    = (short*)(ws + OFF_XBF);   // aliases xbf (dead after gemm1)
  short* wcat = (short*)(ws + OFF_WCAT);
  short* wpp  = (short*)(ws + OFF_WPP);
  short* wout = (short*)(ws + OFF_WOUT);
  float* vecs = (float*)(ws + OFF_VEC);
  float* out  = (float*)d_out;

  cvt_x_k<<<8192, 256, 0, stream>>>(x, xbf);
  prep_w_k<<<4352, 256, 0, stream>>>(W_in, W_x, W_gx, W_dc, W_pp, W_out, wcat, wpp, wout);
  state_k<<<160, 256, 0, stream>>>(prev, W_s, W_dc, b_dc, W_pp, b_pp, W_pg, b_pg, W_gs, b_gs, vecs);
  gemm1sg_k<<<512, 256, 0, stream>>>(xbf, wcat, prev, b_gx, vecs, S, G);
  gemm2h_k<<<256, 256, 0, stream>>>(S, G, wpp, vecs, H, out);
  gemm3_k<<<1024, 256, 0, stream>>>(H, wout, out);
}

// Round 8
// 109.548 us; speedup vs baseline: 1.1746x; 1.0535x over previous
//
#include <hip/hip_runtime.h>
#include <hip/hip_bf16.h>
#include <math.h>

// ---------------------------------------------------------------------------
// GatedTinyMambaLayer: B=8, T=2048, DM=1024, DS=256
// s_prev = broadcast(prev_state) -> per-batch [8,256] precomputes.
// Pipeline (4 launches): prep_all (cvt_x + weight prep + state GEMVs) ->
// gemm1sg (128x96 tile, 1024 blocks, epilogue computes S,G; no Y) ->
// gemm2h -> gemm3.
// wcat row order: 8 groups of 96 rows: group g = {W_in+W_x[g*32..+31],
// W_gx[g*32..+31], W_dc[g*32..+31]} so each block holds the (ix,gx,dc)
// triple for its 32 output cols.
// ---------------------------------------------------------------------------

typedef __attribute__((ext_vector_type(4)))  float f32x4;
typedef __attribute__((ext_vector_type(8)))  short bf16x8;

#define DEV static __device__ __forceinline__

DEV float bf2f(short u) {
  union { float f; unsigned i; } v; v.i = ((unsigned)(unsigned short)u) << 16; return v.f;
}
DEV short f2bf(float f) {  // round-to-nearest-even
  union { float f; unsigned i; } v; v.f = f;
  unsigned x = v.i;
  return (short)((x + 0x7fffu + ((x >> 16) & 1u)) >> 16);
}
DEV unsigned pk_bf16(float lo, float hi) {  // -> v_cvt_pk_bf16_f32
  __hip_bfloat162 h = __float22bfloat162_rn(make_float2(lo, hi));
  return *(unsigned*)&h;
}
DEV float sigmoidf_(float x) { return 1.f / (1.f + expf(-x)); }

DEV void gl16(const void* g, void* l) {
  __builtin_amdgcn_global_load_lds(
      (const __attribute__((address_space(1))) void*)(g),
      (__attribute__((address_space(3))) void*)(l), 16, 0, 0);
}

// stage one 128x32 bf16 subtile pair into linear LDS [128][32] via gload_lds
DEV void stage_tile(const short* gA, const short* gB, short* As, short* Bs,
                    int lda, int ldb, int w, int lane) {
  const int rsub = lane >> 2, kc = (lane & 3) * 8;
#pragma unroll
  for (int j = 0; j < 2; ++j) {
    const int seg = w * 2 + j;           // 0..7, 16 rows each
    const int r = seg * 16 + rsub;
    gl16(gA + (size_t)r * lda + kc, As + seg * 512);
    gl16(gB + (size_t)r * ldb + kc, Bs + seg * 512);
  }
}

DEV void kstep(const short* Asb, const short* Bsb, int wr, int wc, int arow, int ag,
               f32x4 (&acc)[4][4]) {
  bf16x8 af[4], bfv[4];
#pragma unroll
  for (int mi = 0; mi < 4; ++mi)
    af[mi] = *(const bf16x8*)(Asb + (wr * 64 + mi * 16 + arow) * 32 + ag * 8);
#pragma unroll
  for (int ni = 0; ni < 4; ++ni)
    bfv[ni] = *(const bf16x8*)(Bsb + (wc * 64 + ni * 16 + arow) * 32 + ag * 8);
#pragma unroll
  for (int mi = 0; mi < 4; ++mi)
#pragma unroll
    for (int ni = 0; ni < 4; ++ni)
      acc[mi][ni] = __builtin_amdgcn_mfma_f32_16x16x32_bf16(af[mi], bfv[ni], acc[mi][ni], 0, 0, 0);
}

// ---- workspace layout (bytes) ---------------------------------------------
static const size_t OFF_S    = 0;                   // bf16 [16384][256]
static const size_t OFF_G    = 8388608;             // bf16 [16384][256]
static const size_t OFF_XBF  = 25165824;            // bf16 [16384][1024]; H aliases (dead after gemm1)
static const size_t OFF_WCAT = OFF_XBF + 33554432;  // bf16 [768][1024] (96-row groups)
static const size_t OFF_WPP  = OFF_WCAT + 1572864;  // bf16 [256][256]  (W_pp[:, :256])
static const size_t OFF_WOUT = OFF_WPP + 131072;    // bf16 [1024][256]
static const size_t OFF_VEC  = OFF_WOUT + 524288;   // f32 [5][2048]: sdc,sws,spp,pstr,gst

// ---------------------------------------------------------------------------
// prep_all: blocks [0,8192) cvt_x ; [8192,12544) prep_w ; [12544,12704) state
__global__ __launch_bounds__(256, 1) void prep_all_k(
    const float* __restrict__ x, short* __restrict__ xbf,
    const float* __restrict__ W_in, const float* __restrict__ W_x,
    const float* __restrict__ W_gx, const float* __restrict__ W_dc,
    const float* __restrict__ W_pp, const float* __restrict__ W_out,
    short* __restrict__ wcat, short* __restrict__ wpp, short* __restrict__ wout,
    const float* __restrict__ prev, const float* __restrict__ Ws,
    const float* __restrict__ bdc, const float* __restrict__ bpp,
    const float* __restrict__ Wpg, const float* __restrict__ bpg,
    const float* __restrict__ Wgs, const float* __restrict__ bgs,
    float* __restrict__ vecs) {
  const int bid = (int)blockIdx.x, tid = (int)threadIdx.x;
  if (bid < 8192) {  // ---- x f32 -> bf16, 8 elems/thread
    const size_t i = ((size_t)bid * 256 + tid) * 8;
    const float4 a = *(const float4*)(x + i);
    const float4 b = *(const float4*)(x + i + 4);
    uint4 o;
    o.x = pk_bf16(a.x, a.y); o.y = pk_bf16(a.z, a.w);
    o.z = pk_bf16(b.x, b.y); o.w = pk_bf16(b.z, b.w);
    *(uint4*)(xbf + i) = o;
  } else if (bid < 12544) {  // ---- weight prep
    const int idx = (bid - 8192) * 256 + tid;
    const int N_WCAT = 768 * 1024, N_WPP = 256 * 256;
    if (idx < N_WCAT) {
      const int r = idx >> 10, k = idx & 1023;
      const int g = r / 96, j = r % 96;
      float v;
      if (j < 32)      v = W_in[(g * 32 + j) * 1024 + k] + W_x[(g * 32 + j) * 1024 + k];
      else if (j < 64) v = W_gx[(g * 32 + j - 32) * 1024 + k];
      else             v = W_dc[(g * 32 + j - 64) * 1280 + k];
      wcat[idx] = f2bf(v);
    } else if (idx < N_WCAT + N_WPP) {
      const int j = idx - N_WCAT, o = j >> 8, k = j & 255;
      wpp[j] = f2bf(W_pp[o * 512 + k]);          // W_pp[:, :256]
    } else {
      const int j = idx - N_WCAT - N_WPP, o = j >> 8, k = j & 255;
      wout[j] = f2bf(W_out[o * 256 + k]);
    }
  } else {  // ---- per-batch state GEMVs (coalesced, butterfly reduce)
    const int sb = bid - 12544;
    const int b = sb / 20, rem = sb % 20, m = rem >> 2, oq = rem & 3;
    const int lane = tid & 63, w = tid >> 6;
    const float4 sv = *(const float4*)(prev + b * 256 + lane * 4);
    const float* Wb; const float* bias; int stride, off;
    if (m == 0)      { Wb = W_dc; stride = 1280; off = 1024; bias = bdc; }
    else if (m == 1) { Wb = Ws;   stride = 256;  off = 0;    bias = nullptr; }
    else if (m == 2) { Wb = W_pp; stride = 512;  off = 256;  bias = bpp; }
    else if (m == 3) { Wb = Wpg;  stride = 256;  off = 0;    bias = bpg; }
    else             { Wb = Wgs;  stride = 256;  off = 0;    bias = bgs; }
    const int o0 = oq * 64 + w * 16;
#pragma unroll 4
    for (int i = 0; i < 16; ++i) {
      const int o = o0 + i;
      const float4 wv = *(const float4*)(Wb + (size_t)o * stride + off + lane * 4);
      float p = wv.x * sv.x + wv.y * sv.y + wv.z * sv.z + wv.w * sv.w;
#pragma unroll
      for (int d = 32; d >= 1; d >>= 1) p += __shfl_xor(p, d, 64);
      if (lane == 0) {
        float r = (m == 1) ? 0.5f * p : p + bias[o];
        if (m >= 3) r = sigmoidf_(r);
        vecs[m * 2048 + b * 256 + o] = r;
      }
    }
  }
}

// ---------------------------------------------------------------------------
// GEMM1+SG: 128x96 tile, grid = 128 m-tiles x 8 col-groups = 1024 blocks
// (4 blocks/CU). 4 waves, each 32 rows x 96 cols (acc[2][6]). K=1024.
// Epilogue: S = prev*exp(-.05*sig(dc+sdc)) + ix + sws ; G = sig(gx+bgx).
__global__ __launch_bounds__(256) void gemm1sg_k(const short* __restrict__ A,
                                                 const short* __restrict__ Bm,
                                                 const float* __restrict__ prev,
                                                 const float* __restrict__ bgx,
                                                 const float* __restrict__ vecs,
                                                 short* __restrict__ S,
                                                 short* __restrict__ G) {
  __shared__ short As[2][4096];    // [128][32]
  __shared__ short Bs[2][3072];    // [96][32]
  const int tid = (int)threadIdx.x, lane = tid & 63, w = tid >> 6;
  int bid = (int)blockIdx.x;
  bid = (bid & 7) * 128 + (bid >> 3);          // XCD swizzle (1024 % 8 == 0)
  const int mt = bid >> 3, ntg = bid & 7;
  const int m0 = mt * 128, b = m0 >> 11;
  const short* gA = A + (size_t)m0 * 1024;
  const short* gB = Bm + (size_t)(ntg * 96) * 1024;
  const int rsub = lane >> 2, kc = (lane & 3) * 8;

  f32x4 acc[2][6];
#pragma unroll
  for (int mi = 0; mi < 2; ++mi)
#pragma unroll
    for (int ni = 0; ni < 6; ++ni)
#pragma unroll
      for (int r = 0; r < 4; ++r) acc[mi][ni][r] = 0.f;

  // staging: A 512 granules (2/thread); B 384 granules (1/thread + half on w<2)
#define STAGE1(buf, t)                                                        \
  {                                                                           \
    _Pragma("unroll")                                                         \
    for (int j = 0; j < 2; ++j) {                                             \
      const int seg = w * 2 + j;                                              \
      gl16(gA + (size_t)(seg * 16 + rsub) * 1024 + (t) * 32 + kc,             \
           As[buf] + seg * 512);                                              \
    }                                                                         \
    {                                                                         \
      const int Gr = w * 64 + lane;                                           \
      gl16(gB + (size_t)(Gr >> 2) * 1024 + (t) * 32 + ((Gr & 3) * 8),         \
           Bs[buf] + w * 512);                                                \
    }                                                                         \
    if (w < 2) {                                                              \
      const int Gr = 256 + w * 64 + lane;                                     \
      gl16(gB + (size_t)(Gr >> 2) * 1024 + (t) * 32 + ((Gr & 3) * 8),         \
           Bs[buf] + 2048 + w * 512);                                         \
    }                                                                         \
  }

  STAGE1(0, 0);
  __syncthreads();
  const int arow = lane & 15, ag = lane >> 4;
#pragma unroll 1
  for (int t = 0; t < 32; ++t) {
    if (t < 31) STAGE1((t + 1) & 1, t + 1);
    const short* Asb = As[t & 1];
    const short* Bsb = Bs[t & 1];
    bf16x8 af[2];
#pragma unroll
    for (int mi = 0; mi < 2; ++mi)
      af[mi] = *(const bf16x8*)(Asb + (w * 32 + mi * 16 + arow) * 32 + ag * 8);
#pragma unroll
    for (int ni = 0; ni < 6; ++ni) {
      const bf16x8 bf = *(const bf16x8*)(Bsb + (ni * 16 + arow) * 32 + ag * 8);
#pragma unroll
      for (int mi = 0; mi < 2; ++mi)
        acc[mi][ni] = __builtin_amdgcn_mfma_f32_16x16x32_bf16(af[mi], bf, acc[mi][ni], 0, 0, 0);
    }
    __syncthreads();
  }
#undef STAGE1

  // epilogue: B-rows 0..31 = ix, 32..63 = gx, 64..95 = dc (within group ntg)
  const int quad = lane >> 4;
#pragma unroll
  for (int nj = 0; nj < 2; ++nj) {
    const int cg = ntg * 32 + nj * 16 + arow;
    const float sdc = vecs[0 * 2048 + b * 256 + cg];
    const float sws = vecs[1 * 2048 + b * 256 + cg];
    const float pv  = prev[b * 256 + cg];
    const float bg  = bgx[cg];
#pragma unroll
    for (int mi = 0; mi < 2; ++mi)
#pragma unroll
      for (int r = 0; r < 4; ++r) {
        const int row = m0 + w * 32 + mi * 16 + quad * 4 + r;
        const float dec = expf(-0.05f * sigmoidf_(acc[mi][4 + nj][r] + sdc));
        const float sp = pv * dec + acc[mi][nj][r] + sws;
        const float g = sigmoidf_(acc[mi][2 + nj][r] + bg);
        S[(size_t)row * 256 + cg] = f2bf(sp);
        G[(size_t)row * 256 + cg] = f2bf(g);
      }
  }
}

// ---------------------------------------------------------------------------
// GEMM2 + elementwise: P = S @ wpp^T; h = (S + pstr*tanh(P+spp)) * G * gst
__global__ __launch_bounds__(256) void gemm2h_k(const short* __restrict__ S,
                                                const short* __restrict__ G,
                                                const short* __restrict__ Wpp,
                                                const float* __restrict__ vecs,
                                                short* __restrict__ H,
                                                float* __restrict__ out) {
  __shared__ short As[2][4096];
  __shared__ short Bs[2][4096];
  const int tid = (int)threadIdx.x, lane = tid & 63, w = tid >> 6;
  const int wr = w >> 1, wc = w & 1;
  int bid = (int)blockIdx.x;
  bid = (bid & 7) * 32 + (bid >> 3);           // 256 % 8 == 0
  const int m0 = (bid >> 1) * 128, n0 = (bid & 1) * 128;
  const int b = m0 >> 11;
  const short* gA = S + (size_t)m0 * 256;
  const short* gB = Wpp + (size_t)n0 * 256;

  f32x4 acc[4][4];
#pragma unroll
  for (int mi = 0; mi < 4; ++mi)
#pragma unroll
    for (int ni = 0; ni < 4; ++ni)
#pragma unroll
      for (int r = 0; r < 4; ++r) acc[mi][ni][r] = 0.f;

  stage_tile(gA, gB, As[0], Bs[0], 256, 256, w, lane);
  __syncthreads();
  const int arow = lane & 15, ag = lane >> 4;
#pragma unroll 1
  for (int t = 0; t < 8; ++t) {
    if (t < 7)
      stage_tile(gA + (t + 1) * 32, gB + (t + 1) * 32,
                 As[(t + 1) & 1], Bs[(t + 1) & 1], 256, 256, w, lane);
    kstep(As[t & 1], Bs[t & 1], wr, wc, arow, ag, acc);
    __syncthreads();
  }
#pragma unroll
  for (int mi = 0; mi < 4; ++mi)
#pragma unroll
    for (int ni = 0; ni < 4; ++ni) {
      const int col = n0 + wc * 64 + ni * 16 + (lane & 15);
      const float spp  = vecs[2 * 2048 + b * 256 + col];
      const float pstr = vecs[3 * 2048 + b * 256 + col];
      const float gst  = vecs[4 * 2048 + b * 256 + col];
#pragma unroll
      for (int r = 0; r < 4; ++r) {
        const int row = m0 + wr * 64 + mi * 16 + (lane >> 4) * 4 + r;
        const float pv = tanhf(acc[mi][ni][r] + spp);
        const float sp = bf2f(S[(size_t)row * 256 + col]);
        const float h = (sp + pstr * pv) * bf2f(G[(size_t)row * 256 + col]) * gst;
        H[(size_t)row * 256 + col] = f2bf(h);
        if ((row & 2047) == 2047) out[16777216 + b * 256 + col] = h;
      }
    }
}

// ---------------------------------------------------------------------------
// GEMM3: out[16384][1024] f32 = H @ wout^T. K=256 -> 8 k-steps. (m97 form)
__global__ __launch_bounds__(256) void gemm3_k(const short* __restrict__ H,
                                               const short* __restrict__ Wout,
                                               float* __restrict__ out) {
  __shared__ short As[2][4096];
  __shared__ short Bs[2][4096];
  const int tid = (int)threadIdx.x, lane = tid & 63, w = tid >> 6;
  const int wr = w >> 1, wc = w & 1;
  int bid = (int)blockIdx.x;
  bid = (bid & 7) * 128 + (bid >> 3);          // 1024 % 8 == 0
  const int m0 = (bid >> 3) * 128, n0 = (bid & 7) * 128;
  const short* gA = H + (size_t)m0 * 256;
  const short* gB = Wout + (size_t)n0 * 256;

  f32x4 acc[4][4];
#pragma unroll
  for (int mi = 0; mi < 4; ++mi)
#pragma unroll
    for (int ni = 0; ni < 4; ++ni)
#pragma unroll
      for (int r = 0; r < 4; ++r) acc[mi][ni][r] = 0.f;

  stage_tile(gA, gB, As[0], Bs[0], 256, 256, w, lane);
  __syncthreads();
  const int arow = lane & 15, ag = lane >> 4;
#pragma unroll 1
  for (int t = 0; t < 8; ++t) {
    if (t < 7)
      stage_tile(gA + (t + 1) * 32, gB + (t + 1) * 32,
                 As[(t + 1) & 1], Bs[(t + 1) & 1], 256, 256, w, lane);
    kstep(As[t & 1], Bs[t & 1], wr, wc, arow, ag, acc);
    __syncthreads();
  }
#pragma unroll
  for (int mi = 0; mi < 4; ++mi)
#pragma unroll
    for (int ni = 0; ni < 4; ++ni) {
      const int col = n0 + wc * 64 + ni * 16 + (lane & 15);
#pragma unroll
      for (int r = 0; r < 4; ++r) {
        const int row = m0 + wr * 64 + mi * 16 + (lane >> 4) * 4 + r;
        out[(size_t)row * 1024 + col] = acc[mi][ni][r];
      }
    }
}

// ---------------------------------------------------------------------------
extern "C" void kernel_launch(void* const* d_in, const int* in_sizes, int n_in,
                              void* d_out, int out_size, void* d_ws, size_t ws_size,
                              hipStream_t stream) {
  (void)in_sizes; (void)n_in; (void)out_size; (void)ws_size;
  const float* x      = (const float*)d_in[0];
  const float* prev   = (const float*)d_in[1];
  const float* W_in   = (const float*)d_in[2];
  const float* W_x    = (const float*)d_in[3];
  const float* W_s    = (const float*)d_in[4];
  const float* W_out  = (const float*)d_in[5];
  const float* W_gx   = (const float*)d_in[6];
  const float* b_gx   = (const float*)d_in[7];
  const float* W_gs   = (const float*)d_in[8];
  const float* b_gs   = (const float*)d_in[9];
  const float* W_dc   = (const float*)d_in[10];
  const float* b_dc   = (const float*)d_in[11];
  const float* W_pp   = (const float*)d_in[12];
  const float* b_pp   = (const float*)d_in[13];
  const float* W_pg   = (const float*)d_in[14];
  const float* b_pg   = (const float*)d_in[15];

  char* ws = (char*)d_ws;
  short* S    = (short*)(ws + OFF_S);
  short* G    = (short*)(ws + OFF_G);
  short* xbf  = (short*)(ws + OFF_XBF);
  short* H    = (short*)(ws + OFF_XBF);   // aliases xbf (dead after gemm1)
  short* wcat = (short*)(ws + OFF_WCAT);
  short* wpp  = (short*)(ws + OFF_WPP);
  short* wout = (short*)(ws + OFF_WOUT);
  float* vecs = (float*)(ws + OFF_VEC);
  float* out  = (float*)d_out;

  prep_all_k<<<12704, 256, 0, stream>>>(x, xbf, W_in, W_x, W_gx, W_dc, W_pp, W_out,
                                        wcat, wpp, wout, prev, W_s, b_dc, b_pp,
                                        W_pg, b_pg, W_gs, b_gs, vecs);
  gemm1sg_k<<<1024, 256, 0, stream>>>(xbf, wcat, prev, b_gx, vecs, S, G);
  gemm2h_k<<<256, 256, 0, stream>>>(S, G, wpp, vecs, H, out);
  gemm3_k<<<1024, 256, 0, stream>>>(H, wout, out);
}